// Round 10
// baseline (187.391 us; speedup 1.0000x reference)
//
#include <hip/hip_runtime.h>
#include <hip/hip_bf16.h>

// SelfAttention: x[2,2048,1024] fp32; w_qkv[3072,1024]; w_out[1024,1024]; b_out[1024]
// Pipeline:
//  (0) cvt_all: x, w_qkv (q rows pre-scaled by 0.125*log2e), w_out -> bf16 ws
//  (1) gemm128<0,128>: qkv = x @ w_qkv^T. q,k -> qk_ws bf16 [4096,2048];
//      v -> vt_ws transposed [b][h][d][key]
//  (2) attn_kernel (R5 EXACT — verified passing at 58.3 us in round 7):
//      dbuf, one barrier/chunk, V-read hoist, permlane C->A, 2-chain QK,
//      lsum+shfl epilogue.
//  (3) gemm128<1,64>: out = attn @ w_out^T + b_out
// GEMM: BM=128, BK=64, global_load_lds w=16, XOR-swizzle (2-way banks, free).
// 32x32 C/D layout: col=lane&31 (B's n), row=(reg&3)+8*(reg>>2)+4*(lane>>5).
// 32x32 A/B frag: lane&31 = m/n, k = (lane>>5)*8 + j (8 contiguous bf16 = 16 B).
// JOURNAL:
//  - R0: +setprio: 71.1 (lockstep regime, no help). R1: 128-key chunks:
//    neutral + conflicts. R2 WIN: dbuf single-barrier: 61.1.
//  - R5 WIN (measured round 7): V-read hoist + permlane32_swap C->A:
//    attn 58.3 us, total 184.3, VGPR 64, conflicts 0.
//  - R7 FAIL 0.044 (ones-column l). R8 FAIL 0.025 (single-chain QK — change
//    is numerically inert, CANNOT explain 2.5% error!). Joint conclusion:
//    schedule-sensitive corruption around inline-asm permlane (suspected
//    uncovered VALU hazard cvt_pk->permlane across asm boundary). R5's
//    schedule is known-good; binary is deterministic.
//  - R9 (this): resubmit R5 byte-identical as the discriminating experiment.
//    Pass -> my edits induced the failures; permlane region FROZEN.
//    Fail -> latent race in R5 itself; fall back to 2-barrier r7 structure.

#define SEQ   2048
#define BATCH 2
#define CDIM  1024
#define NH    16
#define HD    64
#define NTOK  (BATCH*SEQ)
#define QSCALE 0.18033688011f   // 0.125 * log2(e)

typedef __attribute__((ext_vector_type(8)))  short s16x8;
typedef __attribute__((ext_vector_type(4)))  float f32x4;
typedef __attribute__((ext_vector_type(16))) float f32x16;
typedef __attribute__((ext_vector_type(4)))  unsigned u32x4;
typedef __attribute__((ext_vector_type(2)))  __bf16 bf16x2;

__device__ __forceinline__ short f2bf(float x) {
  unsigned u = __builtin_bit_cast(unsigned, x);
  u = (u + 0x7fffu + ((u >> 16) & 1u)) >> 16;
  return (short)u;
}

// pack two fp32 -> bf16x2 in one u32 (low=a, high=b)
__device__ __forceinline__ unsigned f2bf2(float a, float b) {
#if __has_builtin(__builtin_amdgcn_cvt_pk_bf16_f32)
  bf16x2 v = __builtin_amdgcn_cvt_pk_bf16_f32(a, b);
  return __builtin_bit_cast(unsigned, v);
#else
  unsigned ua = __builtin_bit_cast(unsigned, a) + 0x8000u;
  unsigned ub = __builtin_bit_cast(unsigned, b) + 0x8000u;
  return (ub & 0xffff0000u) | (ua >> 16);
#endif
}

__device__ __forceinline__ float exp2_fast(float x) {
  return __builtin_amdgcn_exp2f(x);   // v_exp_f32
}

__device__ __forceinline__ void gl2lds16(const short* g, short* l) {
  __builtin_amdgcn_global_load_lds(
      (const __attribute__((address_space(1))) void*)g,
      (__attribute__((address_space(3))) void*)l, 16, 0, 0);
}

// ---------------------------------------------------------------------------
// Fused fp32 -> bf16 converts (x | w_qkv(q-scaled) | w_out), 2048 elem/block.
// ---------------------------------------------------------------------------
__global__ __launch_bounds__(256) void cvt_all(
    const float* __restrict__ x, const float* __restrict__ wqkv,
    const float* __restrict__ wout, short* __restrict__ x_bf,
    short* __restrict__ wqkv_bf, short* __restrict__ wout_bf)
{
  int blk = blockIdx.x;
  const float* src; short* dst; int base; float scale = 1.0f;
  if (blk < 2048)      { src = x;    dst = x_bf;    base = blk; }
  else if (blk < 3584) { src = wqkv; dst = wqkv_bf; base = blk - 2048;
                         if (base < 512) scale = QSCALE; }  // q rows
  else                 { src = wout; dst = wout_bf; base = blk - 3584; }
  size_t i = ((size_t)base * 256 + threadIdx.x) * 8;
  float4 v0 = *(const float4*)(src + i);
  float4 v1 = *(const float4*)(src + i + 4);
  s16x8 p;
  p[0]=f2bf(v0.x*scale); p[1]=f2bf(v0.y*scale); p[2]=f2bf(v0.z*scale); p[3]=f2bf(v0.w*scale);
  p[4]=f2bf(v1.x*scale); p[5]=f2bf(v1.y*scale); p[6]=f2bf(v1.z*scale); p[7]=f2bf(v1.w*scale);
  *(s16x8*)(dst + i) = p;
}

// ---------------------------------------------------------------------------
// GEMM: C[M,N] = A[M,K] @ B[N,K]^T, bf16. BM=128, BK=64, 4 waves, 256 thr.
// BN=128: wave 64x64 acc[4][4]; BN=64: wave 64x32 acc[4][2].
// LDS [rows][64] shorts; 16B chunk at (row,pos) holds global chunk
// pos ^ (row&7); frag reads hit bank-group quad^(lrow&7) -> 2-way (free).
// MODE 0: QKV epilogue (q,k -> qk bf16 pitch 2048; v -> vt transposed).
// MODE 1: fp32 + bias epilogue.
// ---------------------------------------------------------------------------
template<int MODE, int BN>
__global__ __launch_bounds__(256) void gemm128(
    const short* __restrict__ A, const short* __restrict__ B,
    const float* __restrict__ bias, void* __restrict__ Cp,
    short* __restrict__ vt, int M, int N, int K)
{
  constexpr int TN = BN / 32;     // acc tiles per wave in N (4 or 2)
  constexpr int NB = BN / 32;     // B-staging gl2lds per thread (4 or 2)

  __shared__ __align__(16) short As[128 * 64];
  __shared__ __align__(16) short Bs[BN * 64];

  const int t    = threadIdx.x;
  const int w    = t >> 6, lane = t & 63;
  const int bm   = blockIdx.y * 128, bn = blockIdx.x * BN;
  const int wm   = (w >> 1) * 64, wn = (w & 1) * (BN / 2);
  const int lrow = lane & 15, quad = lane >> 4;

  int goffA[4], goffB[NB];
#pragma unroll
  for (int i = 0; i < 4; i++) {
    int L   = (w * 4 + i) * 64 + lane;     // 16B-chunk index in 128x64 tile
    int row = L >> 3, pos = L & 7;
    int src = pos ^ (row & 7);
    goffA[i] = (bm + row) * K + src * 8;
  }
#pragma unroll
  for (int i = 0; i < NB; i++) {
    int L   = (w * NB + i) * 64 + lane;
    int row = L >> 3, pos = L & 7;
    int src = pos ^ (row & 7);
    goffB[i] = (bn + row) * K + src * 8;
  }
  const int fk0 = (quad ^ (lrow & 7)) * 8;
  const int fk1 = fk0 ^ 32;

  f32x4 acc[4][TN];
#pragma unroll
  for (int i = 0; i < 4; i++)
#pragma unroll
    for (int j = 0; j < TN; j++) acc[i][j] = (f32x4){0.f, 0.f, 0.f, 0.f};

  for (int k0 = 0; k0 < K; k0 += 64) {
    __syncthreads();
#pragma unroll
    for (int i = 0; i < 4; i++)
      gl2lds16(A + goffA[i] + k0, &As[(w * 4 + i) * 512]);
#pragma unroll
    for (int i = 0; i < NB; i++)
      gl2lds16(B + goffB[i] + k0, &Bs[(w * NB + i) * 512]);
    __syncthreads();

    s16x8 a[4][2], b[TN][2];
#pragma unroll
    for (int tm = 0; tm < 4; tm++) {
      a[tm][0] = *(const s16x8*)&As[(wm + tm * 16 + lrow) * 64 + fk0];
      a[tm][1] = *(const s16x8*)&As[(wm + tm * 16 + lrow) * 64 + fk1];
    }
#pragma unroll
    for (int tn = 0; tn < TN; tn++) {
      b[tn][0] = *(const s16x8*)&Bs[(wn + tn * 16 + lrow) * 64 + fk0];
      b[tn][1] = *(const s16x8*)&Bs[(wn + tn * 16 + lrow) * 64 + fk1];
    }
#pragma unroll
    for (int hh = 0; hh < 2; hh++)
#pragma unroll
      for (int tm = 0; tm < 4; tm++)
#pragma unroll
        for (int tn = 0; tn < TN; tn++)
          acc[tm][tn] = __builtin_amdgcn_mfma_f32_16x16x32_bf16(
              a[tm][hh], b[tn][hh], acc[tm][tn], 0, 0, 0);
  }

  if (MODE == 1) {
#pragma unroll
    for (int tm = 0; tm < 4; tm++)
#pragma unroll
      for (int tn = 0; tn < TN; tn++)
#pragma unroll
        for (int i = 0; i < 4; i++) {
          int row = bm + wm + tm * 16 + quad * 4 + i;
          int col = bn + wn + tn * 16 + lrow;
          ((float*)Cp)[(size_t)row * N + col] = acc[tm][tn][i] + bias[col];
        }
  } else if (bn < 2 * CDIM) {
#pragma unroll
    for (int tm = 0; tm < 4; tm++)
#pragma unroll
      for (int tn = 0; tn < TN; tn++)
#pragma unroll
        for (int i = 0; i < 4; i++) {
          int row = bm + wm + tm * 16 + quad * 4 + i;
          int col = bn + wn + tn * 16 + lrow;
          ((short*)Cp)[(size_t)row * 2048 + col] = f2bf(acc[tm][tn][i]);
        }
  } else {
#pragma unroll
    for (int tm = 0; tm < 4; tm++)
#pragma unroll
      for (int tn = 0; tn < TN; tn++) {
        int vcol = bn - 2 * CDIM + wn + tn * 16 + lrow;
        int h    = vcol >> 6, d = vcol & 63;
        int r0   = bm + wm + tm * 16 + quad * 4;
        int bb   = r0 >> 11, key = r0 & (SEQ - 1);
        size_t off = (((size_t)(bb * NH + h) * HD + d) << 11) + key;
        uint2 pk;
        pk.x = f2bf2(acc[tm][tn][0], acc[tm][tn][1]);
        pk.y = f2bf2(acc[tm][tn][2], acc[tm][tn][3]);
        *(uint2*)(vt + off) = pk;
      }
  }
}

// ---------------------------------------------------------------------------
// Flash attention R5 (verified): r7 geometry, LDS double-buffer, ONE barrier
// per 64-key chunk. 32x32x16 MFMA, 2x2 wave grid (wq=q-half, wk=key-half).
// Iter i: stage chunk i+1 (regs) -> buf^1; issue global loads chunk i+2;
// compute chunk i from buf; __syncthreads; swap. Pitch 72 everywhere
// (r7 staging pattern kr=t>>2, kc=(t&3)*16 — measured 0 conflicts).
// All K AND V frag ds_reads issue up front (V latency hides under softmax).
// C->A via v_permlane32_swap_b32: semantics swap(vdst.row1, vsrc.row0).
// With vdst=a=pg[2k] (keys 8k+4h+0..3 packed) and vsrc=b=pg[2k+1]:
//   new_a = word0/1 of A-frag (h=0: own keys 0-3; h=1: partner keys 8-11)
//   new_b = word2/3            (h=0: partner keys 4-7; h=1: own keys 12-15)
// S^T = mfma(K, Q(regs)) 2 parallel chains; no-max softmax (exp2, scale
// pre-folded). End: cross-wk O/l reduce via LDS.
// FROZEN REGION: softmax->cvt_pk->permlane sequence. Two perturbations of
// this region (R7, R8) produced few-percent corruption not explained by
// their math; suspected uncovered VALU hazard around the asm. Do not
// reorder/modify without a dedicated probe.
// ---------------------------------------------------------------------------
#define KPITCH 72
#define ABUFSZ (2 * 64 * KPITCH)   // Ks+Vs per buffer = 9216 shorts (18 KB)

__global__ __launch_bounds__(256, 4) void attn_kernel(
    const short* __restrict__ qk, const short* __restrict__ vt,
    short* __restrict__ attn_out)
{
  __shared__ __align__(16) short smem[2 * ABUFSZ];   // 36 KB

  const int t   = threadIdx.x;
  const int w   = t >> 6, lane = t & 63;
  const int l31 = lane & 31, h = lane >> 5;
  const int wq  = w & 1, wk = w >> 1;
  const int bh  = blockIdx.x;
  const int b   = bh >> 4, hd = bh & (NH - 1);
  const int q0  = blockIdx.y * 64;

  const short* base  = qk + (size_t)(b * SEQ) * 2048 + hd * HD;
  const short* vbase = vt + ((size_t)(b * NH + hd) * HD) * SEQ;

  // Q B-frags in registers (pre-scaled): n=q, k=d=c*16+h*8+j
  s16x8 qf[4];
  {
    const short* qp = base + (size_t)(q0 + wq * 32 + l31) * 2048;
#pragma unroll
    for (int c = 0; c < 4; c++) qf[c] = *(const s16x8*)(qp + c * 16 + h * 8);
  }

  f32x16 o0 = {}, o1 = {};
  float lsum = 0.f;

  const int kr = t >> 2, kc = (t & 3) * 16;   // staging: 64 rows x 64, 16/thr

  s16x8 pk0, pk1, pv0, pv1;
  // load chunk 0
  {
    const short* kp = base + (size_t)kr * 2048 + CDIM + kc;
    pk0 = *(const s16x8*)kp; pk1 = *(const s16x8*)(kp + 8);
    const short* vp = vbase + (size_t)kr * SEQ + kc;
    pv0 = *(const s16x8*)vp; pv1 = *(const s16x8*)(vp + 8);
  }
  // stage chunk 0 into buf0
  {
    short* Ks0 = smem;
    short* Vs0 = smem + 64 * KPITCH;
    *(s16x8*)&Ks0[kr * KPITCH + kc]     = pk0;
    *(s16x8*)&Ks0[kr * KPITCH + kc + 8] = pk1;
    *(s16x8*)&Vs0[kr * KPITCH + kc]     = pv0;
    *(s16x8*)&Vs0[kr * KPITCH + kc + 8] = pv1;
  }
  __syncthreads();
  // load chunk 1
  {
    const short* kp = base + (size_t)(64 + kr) * 2048 + CDIM + kc;
    pk0 = *(const s16x8*)kp; pk1 = *(const s16x8*)(kp + 8);
    const short* vp = vbase + (size_t)kr * SEQ + 64 + kc;
    pv0 = *(const s16x8*)vp; pv1 = *(const s16x8*)(vp + 8);
  }

  int cur = 0;
  for (int i = 0; i < SEQ / 64; i++) {
    short* Ksc = smem + cur * ABUFSZ;
    short* Vsc = Ksc + 64 * KPITCH;

    // stage chunk i+1 (in regs) into next buffer — overlaps compute below
    if (i <= SEQ / 64 - 2) {
      short* Ksn = smem + (cur ^ 1) * ABUFSZ;
      short* Vsn = Ksn + 64 * KPITCH;
      *(s16x8*)&Ksn[kr * KPITCH + kc]     = pk0;
      *(s16x8*)&Ksn[kr * KPITCH + kc + 8] = pk1;
      *(s16x8*)&Vsn[kr * KPITCH + kc]     = pv0;
      *(s16x8*)&Vsn[kr * KPITCH + kc + 8] = pv1;
    }

    // issue global loads for chunk i+2 (in flight across compute + barrier)
    if (i <= SEQ / 64 - 3) {
      int nn = (i + 2) * 64;
      const short* kp = base + (size_t)(nn + kr) * 2048 + CDIM + kc;
      pk0 = *(const s16x8*)kp; pk1 = *(const s16x8*)(kp + 8);
      const short* vp = vbase + (size_t)kr * SEQ + nn + kc;
      pv0 = *(const s16x8*)vp; pv1 = *(const s16x8*)(vp + 8);
    }

    // --- issue ALL frag reads up front: K for QK, V for PV (latency of V
    //     hides under the softmax VALU block) ---
    const short* kbase = &Ksc[(wk * 32 + l31) * KPITCH + h * 8];
    s16x8 kf0 = *(const s16x8*)(kbase + 0);
    s16x8 kf1 = *(const s16x8*)(kbase + 16);
    s16x8 kf2 = *(const s16x8*)(kbase + 32);
    s16x8 kf3 = *(const s16x8*)(kbase + 48);
    s16x8 va0 = *(const s16x8*)&Vsc[l31 * KPITCH        + wk * 32 + h * 8];
    s16x8 va1 = *(const s16x8*)&Vsc[(32 + l31) * KPITCH + wk * 32 + h * 8];
    s16x8 vb0 = *(const s16x8*)&Vsc[l31 * KPITCH        + wk * 32 + 16 + h * 8];
    s16x8 vb1 = *(const s16x8*)&Vsc[(32 + l31) * KPITCH + wk * 32 + 16 + h * 8];

    // S^T[key][q]: A = K rows (wk half), B = Q regs. Two parallel chains.
    f32x16 sa = {}, sb = {};
    sa = __builtin_amdgcn_mfma_f32_32x32x16_bf16(kf0, qf[0], sa, 0, 0, 0);
    sb = __builtin_amdgcn_mfma_f32_32x32x16_bf16(kf2, qf[2], sb, 0, 0, 0);
    sa = __builtin_amdgcn_mfma_f32_32x32x16_bf16(kf1, qf[1], sa, 0, 0, 0);
    sb = __builtin_amdgcn_mfma_f32_32x32x16_bf16(kf3, qf[3], sb, 0, 0, 0);

    // softmax + pack: reg r -> key (r&3)+8*(r>>2)+4h (local to wave's half)
    uint2 pg[4];
#pragma unroll
    for (int g = 0; g < 4; g++) {
      float p0 = exp2_fast(sa[4 * g + 0] + sb[4 * g + 0]);
      float p1 = exp2_fast(sa[4 * g + 1] + sb[4 * g + 1]);
      float p2 = exp2_fast(sa[4 * g + 2] + sb[4 * g + 2]);
      float p3 = exp2_fast(sa[4 * g + 3] + sb[4 * g + 3]);
      lsum += (p0 + p1) + (p2 + p3);
      pg[g].x = f2bf2(p0, p1);
      pg[g].y = f2bf2(p2, p3);
    }

    // C->A via permlane32_swap (vdst=a=low-keys, vsrc=b=high-keys):
    //   new_a -> A-frag word0/1, new_b -> word2/3
    s16x8 pf[2];
#pragma unroll
    for (int kc2 = 0; kc2 < 2; kc2++) {
      unsigned a0 = pg[2 * kc2].x,     a1 = pg[2 * kc2].y;
      unsigned b0 = pg[2 * kc2 + 1].x, b1 = pg[2 * kc2 + 1].y;
      asm("v_permlane32_swap_b32 %0, %1" : "+v"(a0), "+v"(b0));
      asm("v_permlane32_swap_b32 %0, %1" : "+v"(a1), "+v"(b1));
      u32x4 f = {a0, a1, b0, b1};
      pf[kc2] = __builtin_bit_cast(s16x8, f);
    }

    // PV: O[q][d] += P * V over wave's 32 keys; B-frags preloaded above
    o0 = __builtin_amdgcn_mfma_f32_32x32x16_bf16(pf[0], va0, o0, 0, 0, 0);
    o1 = __builtin_amdgcn_mfma_f32_32x32x16_bf16(pf[0], va1, o1, 0, 0, 0);
    o0 = __builtin_amdgcn_mfma_f32_32x32x16_bf16(pf[1], vb0, o0, 0, 0, 0);
    o1 = __builtin_amdgcn_mfma_f32_32x32x16_bf16(pf[1], vb1, o1, 0, 0, 0);

    __syncthreads();                 // one barrier per chunk
    cur ^= 1;
  }

  // ---- epilogue: cross-wk reduction of O and l, normalize, store ----
  lsum += __shfl_xor(lsum, 32);          // combine h halves (disjoint keys)

  float* Ored = (float*)smem;            // [2 wq][32 q][64 d] = 16 KB
  float* Lred = (float*)smem + 4096;     // [64]

  if (wk == 0) {
#pragma unroll
    for (int r = 0; r < 16; r++) {
      int ql = (r & 3) + 8 * (r >> 2) + 4 * h;
      Ored[(wq * 32 + ql) * 64 + l31]      = o0[r];
      Ored[(wq * 32 + ql) * 64 + 32 + l31] = o1[r];
    }
    if (lane < 32) Lred[wq * 32 + l31] = lsum;
  }
  __syncthreads();
  if (wk == 1 && lane < 32) Lred[wq * 32 + l31] += lsum;
  __syncthreads();
  if (wk == 1) {
#pragma unroll
    for (int r = 0; r < 16; r++) {
      int ql = (r & 3) + 8 * (r >> 2) + 4 * h;
      float linv = 1.0f / Lred[wq * 32 + ql];
      int qg = q0 + wq * 32 + ql;
      size_t rowb = (size_t)(b * SEQ + qg) * CDIM + hd * HD;
      float v0 = (o0[r] + Ored[(wq * 32 + ql) * 64 + l31]) * linv;
      float v1 = (o1[r] + Ored[(wq * 32 + ql) * 64 + 32 + l31]) * linv;
      attn_out[rowb + l31]      = f2bf(v0);
      attn_out[rowb + 32 + l31] = f2bf(v1);
    }
  }
}

// ---------------------------------------------------------------------------
extern "C" void kernel_launch(void* const* d_in, const int* in_sizes, int n_in,
                              void* d_out, int out_size, void* d_ws, size_t ws_size,
                              hipStream_t stream)
{
  const float* x     = (const float*)d_in[0];
  const float* w_qkv = (const float*)d_in[1];
  const float* w_out = (const float*)d_in[2];
  const float* b_out = (const float*)d_in[3];

  short* qk_ws   = (short*)d_ws;                         // 4096*2048 = 16 MB
  short* vt_ws   = qk_ws  + (size_t)NTOK * 2048;         // 4096*1024 =  8 MB
  short* x_bf    = vt_ws  + (size_t)NTOK * CDIM;         // 4096*1024 =  8 MB
  short* attn_ws = x_bf;                                 // alias (x_bf dead)
  short* wqkv_bf = x_bf   + (size_t)NTOK * CDIM;         // 3072*1024 =  6 MB
  short* wout_bf = wqkv_bf + (size_t)3 * CDIM * CDIM;    // 1024*1024 =  2 MB

  dim3 blk(256);

  cvt_all<<<dim3(4096), blk, 0, stream>>>(x, w_qkv, w_out, x_bf, wqkv_bf, wout_bf);

  gemm128<0, 128><<<dim3(3 * CDIM / 128, NTOK / 128), blk, 0, stream>>>(
      x_bf, wqkv_bf, nullptr, qk_ws, vt_ws, NTOK, 3 * CDIM, CDIM);

  attn_kernel<<<dim3(BATCH * NH, SEQ / 64), blk, 0, stream>>>(qk_ws, vt_ws, attn_ws);

  gemm128<1, 64><<<dim3(CDIM / 64, NTOK / 128), blk, 0, stream>>>(
      attn_ws, wout_bf, b_out, d_out, nullptr, NTOK, CDIM, CDIM);
}

// Round 11
// 181.396 us; speedup vs baseline: 1.0331x; 1.0331x over previous
//
#include <hip/hip_runtime.h>
#include <hip/hip_bf16.h>

// SelfAttention: x[2,2048,1024] fp32; w_qkv[3072,1024]; w_out[1024,1024]; b_out[1024]
// Pipeline:
//  (0) cvt_all: x, w_qkv (q rows pre-scaled by 0.125*log2e), w_out -> bf16 ws
//  (1) gemm128<0,128>: qkv = x @ w_qkv^T. q,k -> qk_ws bf16 [4096,2048];
//      v -> vt_ws transposed [b][h][d][key]. R10: +XCD-chunked swizzle (T1).
//  (2) attn_kernel (R5 EXACT — verified passing twice, 58.3/58.2 us):
//      dbuf, one barrier/chunk, V-read hoist, permlane C->A, 2-chain QK,
//      lsum+shfl epilogue. BYTE-IDENTICAL to round 10 — FROZEN.
//  (3) gemm128<1,64>: out = attn @ w_out^T + b_out. R10: +XCD swizzle.
// GEMM: BM=128, BK=64, global_load_lds w=16, XOR-swizzle (2-way banks, free).
// 32x32 C/D layout: col=lane&31 (B's n), row=(reg&3)+8*(reg>>2)+4*(lane>>5).
// 32x32 A/B frag: lane&31 = m/n, k = (lane>>5)*8 + j (8 contiguous bf16 = 16 B).
// JOURNAL:
//  - R0: +setprio: 71.1 (lockstep, no help). R1: 128-key chunks: neutral +
//    conflicts. R2 WIN: dbuf single-barrier: 61.1.
//  - R5 WIN: V-read hoist + permlane32_swap: attn 58.3, total 184.3.
//  - R7 FAIL 0.044 / R8 FAIL 0.025: both perturbed softmax->permlane region;
//    R8's change was numerically inert -> schedule-induced corruption
//    (suspected VALU hazard across asm boundary). R9/R10: R5 byte-identical
//    PASSED again (58.2) -> attn inner loop FROZEN.
//  - R10 run-to-run noise on identical binary: total 184.3 vs 187.4 (+-1.7%).
//  - R10 (this): T1 XCD-chunked swizzle on both GEMMs (bijective, nwg%8==0).
//    Attn kernel untouched. Probe: null result => GEMM L2 locality not the
//    lever; inputs are L3-resident.

#define SEQ   2048
#define BATCH 2
#define CDIM  1024
#define NH    16
#define HD    64
#define NTOK  (BATCH*SEQ)
#define QSCALE 0.18033688011f   // 0.125 * log2(e)

typedef __attribute__((ext_vector_type(8)))  short s16x8;
typedef __attribute__((ext_vector_type(4)))  float f32x4;
typedef __attribute__((ext_vector_type(16))) float f32x16;
typedef __attribute__((ext_vector_type(4)))  unsigned u32x4;
typedef __attribute__((ext_vector_type(2)))  __bf16 bf16x2;

__device__ __forceinline__ short f2bf(float x) {
  unsigned u = __builtin_bit_cast(unsigned, x);
  u = (u + 0x7fffu + ((u >> 16) & 1u)) >> 16;
  return (short)u;
}

// pack two fp32 -> bf16x2 in one u32 (low=a, high=b)
__device__ __forceinline__ unsigned f2bf2(float a, float b) {
#if __has_builtin(__builtin_amdgcn_cvt_pk_bf16_f32)
  bf16x2 v = __builtin_amdgcn_cvt_pk_bf16_f32(a, b);
  return __builtin_bit_cast(unsigned, v);
#else
  unsigned ua = __builtin_bit_cast(unsigned, a) + 0x8000u;
  unsigned ub = __builtin_bit_cast(unsigned, b) + 0x8000u;
  return (ub & 0xffff0000u) | (ua >> 16);
#endif
}

__device__ __forceinline__ float exp2_fast(float x) {
  return __builtin_amdgcn_exp2f(x);   // v_exp_f32
}

__device__ __forceinline__ void gl2lds16(const short* g, short* l) {
  __builtin_amdgcn_global_load_lds(
      (const __attribute__((address_space(1))) void*)g,
      (__attribute__((address_space(3))) void*)l, 16, 0, 0);
}

// ---------------------------------------------------------------------------
// Fused fp32 -> bf16 converts (x | w_qkv(q-scaled) | w_out), 2048 elem/block.
// ---------------------------------------------------------------------------
__global__ __launch_bounds__(256) void cvt_all(
    const float* __restrict__ x, const float* __restrict__ wqkv,
    const float* __restrict__ wout, short* __restrict__ x_bf,
    short* __restrict__ wqkv_bf, short* __restrict__ wout_bf)
{
  int blk = blockIdx.x;
  const float* src; short* dst; int base; float scale = 1.0f;
  if (blk < 2048)      { src = x;    dst = x_bf;    base = blk; }
  else if (blk < 3584) { src = wqkv; dst = wqkv_bf; base = blk - 2048;
                         if (base < 512) scale = QSCALE; }  // q rows
  else                 { src = wout; dst = wout_bf; base = blk - 3584; }
  size_t i = ((size_t)base * 256 + threadIdx.x) * 8;
  float4 v0 = *(const float4*)(src + i);
  float4 v1 = *(const float4*)(src + i + 4);
  s16x8 p;
  p[0]=f2bf(v0.x*scale); p[1]=f2bf(v0.y*scale); p[2]=f2bf(v0.z*scale); p[3]=f2bf(v0.w*scale);
  p[4]=f2bf(v1.x*scale); p[5]=f2bf(v1.y*scale); p[6]=f2bf(v1.z*scale); p[7]=f2bf(v1.w*scale);
  *(s16x8*)(dst + i) = p;
}

// ---------------------------------------------------------------------------
// GEMM: C[M,N] = A[M,K] @ B[N,K]^T, bf16. BM=128, BK=64, 4 waves, 256 thr.
// BN=128: wave 64x64 acc[4][4]; BN=64: wave 64x32 acc[4][2].
// LDS [rows][64] shorts; 16B chunk at (row,pos) holds global chunk
// pos ^ (row&7); frag reads hit bank-group quad^(lrow&7) -> 2-way (free).
// R10: XCD-chunked blockIdx swizzle (T1) — id%8 = XCD; each XCD gets a
// contiguous row-chunk of the tile grid (A-panel reuse in its private L2).
// Requires nwg%8==0: QKV 768 ok, proj 512 ok.
// MODE 0: QKV epilogue (q,k -> qk bf16 pitch 2048; v -> vt transposed).
// MODE 1: fp32 + bias epilogue.
// ---------------------------------------------------------------------------
template<int MODE, int BN>
__global__ __launch_bounds__(256) void gemm128(
    const short* __restrict__ A, const short* __restrict__ B,
    const float* __restrict__ bias, void* __restrict__ Cp,
    short* __restrict__ vt, int M, int N, int K)
{
  constexpr int TN = BN / 32;     // acc tiles per wave in N (4 or 2)
  constexpr int NB = BN / 32;     // B-staging gl2lds per thread (4 or 2)

  __shared__ __align__(16) short As[128 * 64];
  __shared__ __align__(16) short Bs[BN * 64];

  const int t    = threadIdx.x;
  const int w    = t >> 6, lane = t & 63;

  // T1 XCD-chunked swizzle: physical id%8 = XCD -> contiguous tile chunk.
  const int nwgx = gridDim.x;
  const int id   = blockIdx.y * nwgx + blockIdx.x;
  const int cpx  = (nwgx * gridDim.y) >> 3;
  const int swz  = (id & 7) * cpx + (id >> 3);
  const int bm   = (swz / nwgx) * 128, bn = (swz % nwgx) * BN;

  const int wm   = (w >> 1) * 64, wn = (w & 1) * (BN / 2);
  const int lrow = lane & 15, quad = lane >> 4;

  int goffA[4], goffB[NB];
#pragma unroll
  for (int i = 0; i < 4; i++) {
    int L   = (w * 4 + i) * 64 + lane;     // 16B-chunk index in 128x64 tile
    int row = L >> 3, pos = L & 7;
    int src = pos ^ (row & 7);
    goffA[i] = (bm + row) * K + src * 8;
  }
#pragma unroll
  for (int i = 0; i < NB; i++) {
    int L   = (w * NB + i) * 64 + lane;
    int row = L >> 3, pos = L & 7;
    int src = pos ^ (row & 7);
    goffB[i] = (bn + row) * K + src * 8;
  }
  const int fk0 = (quad ^ (lrow & 7)) * 8;
  const int fk1 = fk0 ^ 32;

  f32x4 acc[4][TN];
#pragma unroll
  for (int i = 0; i < 4; i++)
#pragma unroll
    for (int j = 0; j < TN; j++) acc[i][j] = (f32x4){0.f, 0.f, 0.f, 0.f};

  for (int k0 = 0; k0 < K; k0 += 64) {
    __syncthreads();
#pragma unroll
    for (int i = 0; i < 4; i++)
      gl2lds16(A + goffA[i] + k0, &As[(w * 4 + i) * 512]);
#pragma unroll
    for (int i = 0; i < NB; i++)
      gl2lds16(B + goffB[i] + k0, &Bs[(w * NB + i) * 512]);
    __syncthreads();

    s16x8 a[4][2], b[TN][2];
#pragma unroll
    for (int tm = 0; tm < 4; tm++) {
      a[tm][0] = *(const s16x8*)&As[(wm + tm * 16 + lrow) * 64 + fk0];
      a[tm][1] = *(const s16x8*)&As[(wm + tm * 16 + lrow) * 64 + fk1];
    }
#pragma unroll
    for (int tn = 0; tn < TN; tn++) {
      b[tn][0] = *(const s16x8*)&Bs[(wn + tn * 16 + lrow) * 64 + fk0];
      b[tn][1] = *(const s16x8*)&Bs[(wn + tn * 16 + lrow) * 64 + fk1];
    }
#pragma unroll
    for (int hh = 0; hh < 2; hh++)
#pragma unroll
      for (int tm = 0; tm < 4; tm++)
#pragma unroll
        for (int tn = 0; tn < TN; tn++)
          acc[tm][tn] = __builtin_amdgcn_mfma_f32_16x16x32_bf16(
              a[tm][hh], b[tn][hh], acc[tm][tn], 0, 0, 0);
  }

  if (MODE == 1) {
#pragma unroll
    for (int tm = 0; tm < 4; tm++)
#pragma unroll
      for (int tn = 0; tn < TN; tn++)
#pragma unroll
        for (int i = 0; i < 4; i++) {
          int row = bm + wm + tm * 16 + quad * 4 + i;
          int col = bn + wn + tn * 16 + lrow;
          ((float*)Cp)[(size_t)row * N + col] = acc[tm][tn][i] + bias[col];
        }
  } else if (bn < 2 * CDIM) {
#pragma unroll
    for (int tm = 0; tm < 4; tm++)
#pragma unroll
      for (int tn = 0; tn < TN; tn++)
#pragma unroll
        for (int i = 0; i < 4; i++) {
          int row = bm + wm + tm * 16 + quad * 4 + i;
          int col = bn + wn + tn * 16 + lrow;
          ((short*)Cp)[(size_t)row * 2048 + col] = f2bf(acc[tm][tn][i]);
        }
  } else {
#pragma unroll
    for (int tm = 0; tm < 4; tm++)
#pragma unroll
      for (int tn = 0; tn < TN; tn++) {
        int vcol = bn - 2 * CDIM + wn + tn * 16 + lrow;
        int h    = vcol >> 6, d = vcol & 63;
        int r0   = bm + wm + tm * 16 + quad * 4;
        int bb   = r0 >> 11, key = r0 & (SEQ - 1);
        size_t off = (((size_t)(bb * NH + h) * HD + d) << 11) + key;
        uint2 pk;
        pk.x = f2bf2(acc[tm][tn][0], acc[tm][tn][1]);
        pk.y = f2bf2(acc[tm][tn][2], acc[tm][tn][3]);
        *(uint2*)(vt + off) = pk;
      }
  }
}

// ---------------------------------------------------------------------------
// Flash attention R5 (verified twice): r7 geometry, LDS double-buffer, ONE
// barrier per 64-key chunk. 32x32x16 MFMA, 2x2 wave grid (wq, wk).
// Iter i: stage chunk i+1 (regs) -> buf^1; issue global loads chunk i+2;
// compute chunk i from buf; __syncthreads; swap. Pitch 72 everywhere
// (r7 staging pattern kr=t>>2, kc=(t&3)*16 — measured 0 conflicts).
// All K AND V frag ds_reads issue up front (V latency hides under softmax).
// C->A via v_permlane32_swap_b32 (vdst=low-keys, vsrc=high-keys).
// FROZEN REGION: softmax->cvt_pk->permlane->PV. R7/R8 perturbations both
// corrupted output (schedule-sensitive; suspected VALU hazard). DO NOT EDIT.
// ---------------------------------------------------------------------------
#define KPITCH 72
#define ABUFSZ (2 * 64 * KPITCH)   // Ks+Vs per buffer = 9216 shorts (18 KB)

__global__ __launch_bounds__(256, 4) void attn_kernel(
    const short* __restrict__ qk, const short* __restrict__ vt,
    short* __restrict__ attn_out)
{
  __shared__ __align__(16) short smem[2 * ABUFSZ];   // 36 KB

  const int t   = threadIdx.x;
  const int w   = t >> 6, lane = t & 63;
  const int l31 = lane & 31, h = lane >> 5;
  const int wq  = w & 1, wk = w >> 1;
  const int bh  = blockIdx.x;
  const int b   = bh >> 4, hd = bh & (NH - 1);
  const int q0  = blockIdx.y * 64;

  const short* base  = qk + (size_t)(b * SEQ) * 2048 + hd * HD;
  const short* vbase = vt + ((size_t)(b * NH + hd) * HD) * SEQ;

  // Q B-frags in registers (pre-scaled): n=q, k=d=c*16+h*8+j
  s16x8 qf[4];
  {
    const short* qp = base + (size_t)(q0 + wq * 32 + l31) * 2048;
#pragma unroll
    for (int c = 0; c < 4; c++) qf[c] = *(const s16x8*)(qp + c * 16 + h * 8);
  }

  f32x16 o0 = {}, o1 = {};
  float lsum = 0.f;

  const int kr = t >> 2, kc = (t & 3) * 16;   // staging: 64 rows x 64, 16/thr

  s16x8 pk0, pk1, pv0, pv1;
  // load chunk 0
  {
    const short* kp = base + (size_t)kr * 2048 + CDIM + kc;
    pk0 = *(const s16x8*)kp; pk1 = *(const s16x8*)(kp + 8);
    const short* vp = vbase + (size_t)kr * SEQ + kc;
    pv0 = *(const s16x8*)vp; pv1 = *(const s16x8*)(vp + 8);
  }
  // stage chunk 0 into buf0
  {
    short* Ks0 = smem;
    short* Vs0 = smem + 64 * KPITCH;
    *(s16x8*)&Ks0[kr * KPITCH + kc]     = pk0;
    *(s16x8*)&Ks0[kr * KPITCH + kc + 8] = pk1;
    *(s16x8*)&Vs0[kr * KPITCH + kc]     = pv0;
    *(s16x8*)&Vs0[kr * KPITCH + kc + 8] = pv1;
  }
  __syncthreads();
  // load chunk 1
  {
    const short* kp = base + (size_t)(64 + kr) * 2048 + CDIM + kc;
    pk0 = *(const s16x8*)kp; pk1 = *(const s16x8*)(kp + 8);
    const short* vp = vbase + (size_t)kr * SEQ + 64 + kc;
    pv0 = *(const s16x8*)vp; pv1 = *(const s16x8*)(vp + 8);
  }

  int cur = 0;
  for (int i = 0; i < SEQ / 64; i++) {
    short* Ksc = smem + cur * ABUFSZ;
    short* Vsc = Ksc + 64 * KPITCH;

    // stage chunk i+1 (in regs) into next buffer — overlaps compute below
    if (i <= SEQ / 64 - 2) {
      short* Ksn = smem + (cur ^ 1) * ABUFSZ;
      short* Vsn = Ksn + 64 * KPITCH;
      *(s16x8*)&Ksn[kr * KPITCH + kc]     = pk0;
      *(s16x8*)&Ksn[kr * KPITCH + kc + 8] = pk1;
      *(s16x8*)&Vsn[kr * KPITCH + kc]     = pv0;
      *(s16x8*)&Vsn[kr * KPITCH + kc + 8] = pv1;
    }

    // issue global loads for chunk i+2 (in flight across compute + barrier)
    if (i <= SEQ / 64 - 3) {
      int nn = (i + 2) * 64;
      const short* kp = base + (size_t)(nn + kr) * 2048 + CDIM + kc;
      pk0 = *(const s16x8*)kp; pk1 = *(const s16x8*)(kp + 8);
      const short* vp = vbase + (size_t)kr * SEQ + nn + kc;
      pv0 = *(const s16x8*)vp; pv1 = *(const s16x8*)(vp + 8);
    }

    // --- issue ALL frag reads up front: K for QK, V for PV (latency of V
    //     hides under the softmax VALU block) ---
    const short* kbase = &Ksc[(wk * 32 + l31) * KPITCH + h * 8];
    s16x8 kf0 = *(const s16x8*)(kbase + 0);
    s16x8 kf1 = *(const s16x8*)(kbase + 16);
    s16x8 kf2 = *(const s16x8*)(kbase + 32);
    s16x8 kf3 = *(const s16x8*)(kbase + 48);
    s16x8 va0 = *(const s16x8*)&Vsc[l31 * KPITCH        + wk * 32 + h * 8];
    s16x8 va1 = *(const s16x8*)&Vsc[(32 + l31) * KPITCH + wk * 32 + h * 8];
    s16x8 vb0 = *(const s16x8*)&Vsc[l31 * KPITCH        + wk * 32 + 16 + h * 8];
    s16x8 vb1 = *(const s16x8*)&Vsc[(32 + l31) * KPITCH + wk * 32 + 16 + h * 8];

    // S^T[key][q]: A = K rows (wk half), B = Q regs. Two parallel chains.
    f32x16 sa = {}, sb = {};
    sa = __builtin_amdgcn_mfma_f32_32x32x16_bf16(kf0, qf[0], sa, 0, 0, 0);
    sb = __builtin_amdgcn_mfma_f32_32x32x16_bf16(kf2, qf[2], sb, 0, 0, 0);
    sa = __builtin_amdgcn_mfma_f32_32x32x16_bf16(kf1, qf[1], sa, 0, 0, 0);
    sb = __builtin_amdgcn_mfma_f32_32x32x16_bf16(kf3, qf[3], sb, 0, 0, 0);

    // softmax + pack: reg r -> key (r&3)+8*(r>>2)+4h (local to wave's half)
    uint2 pg[4];
#pragma unroll
    for (int g = 0; g < 4; g++) {
      float p0 = exp2_fast(sa[4 * g + 0] + sb[4 * g + 0]);
      float p1 = exp2_fast(sa[4 * g + 1] + sb[4 * g + 1]);
      float p2 = exp2_fast(sa[4 * g + 2] + sb[4 * g + 2]);
      float p3 = exp2_fast(sa[4 * g + 3] + sb[4 * g + 3]);
      lsum += (p0 + p1) + (p2 + p3);
      pg[g].x = f2bf2(p0, p1);
      pg[g].y = f2bf2(p2, p3);
    }

    // C->A via permlane32_swap (vdst=a=low-keys, vsrc=b=high-keys):
    //   new_a -> A-frag word0/1, new_b -> word2/3
    s16x8 pf[2];
#pragma unroll
    for (int kc2 = 0; kc2 < 2; kc2++) {
      unsigned a0 = pg[2 * kc2].x,     a1 = pg[2 * kc2].y;
      unsigned b0 = pg[2 * kc2 + 1].x, b1 = pg[2 * kc2 + 1].y;
      asm("v_permlane32_swap_b32 %0, %1" : "+v"(a0), "+v"(b0));
      asm("v_permlane32_swap_b32 %0, %1" : "+v"(a1), "+v"(b1));
      u32x4 f = {a0, a1, b0, b1};
      pf[kc2] = __builtin_bit_cast(s16x8, f);
    }

    // PV: O[q][d] += P * V over wave's 32 keys; B-frags preloaded above
    o0 = __builtin_amdgcn_mfma_f32_32x32x16_bf16(pf[0], va0, o0, 0, 0, 0);
    o1 = __builtin_amdgcn_mfma_f32_32x32x16_bf16(pf[0], va1, o1, 0, 0, 0);
    o0 = __builtin_amdgcn_mfma_f32_32x32x16_bf16(pf[1], vb0, o0, 0, 0, 0);
    o1 = __builtin_amdgcn_mfma_f32_32x32x16_bf16(pf[1], vb1, o1, 0, 0, 0);

    __syncthreads();                 // one barrier per chunk
    cur ^= 1;
  }

  // ---- epilogue: cross-wk reduction of O and l, normalize, store ----
  lsum += __shfl_xor(lsum, 32);          // combine h halves (disjoint keys)

  float* Ored = (float*)smem;            // [2 wq][32 q][64 d] = 16 KB
  float* Lred = (float*)smem + 4096;     // [64]

  if (wk == 0) {
#pragma unroll
    for (int r = 0; r < 16; r++) {
      int ql = (r & 3) + 8 * (r >> 2) + 4 * h;
      Ored[(wq * 32 + ql) * 64 + l31]      = o0[r];
      Ored[(wq * 32 + ql) * 64 + 32 + l31] = o1[r];
    }
    if (lane < 32) Lred[wq * 32 + l31] = lsum;
  }
  __syncthreads();
  if (wk == 1 && lane < 32) Lred[wq * 32 + l31] += lsum;
  __syncthreads();
  if (wk == 1) {
#pragma unroll
    for (int r = 0; r < 16; r++) {
      int ql = (r & 3) + 8 * (r >> 2) + 4 * h;
      float linv = 1.0f / Lred[wq * 32 + ql];
      int qg = q0 + wq * 32 + ql;
      size_t rowb = (size_t)(b * SEQ + qg) * CDIM + hd * HD;
      float v0 = (o0[r] + Ored[(wq * 32 + ql) * 64 + l31]) * linv;
      float v1 = (o1[r] + Ored[(wq * 32 + ql) * 64 + 32 + l31]) * linv;
      attn_out[rowb + l31]      = f2bf(v0);
      attn_out[rowb + 32 + l31] = f2bf(v1);
    }
  }
}

// ---------------------------------------------------------------------------
extern "C" void kernel_launch(void* const* d_in, const int* in_sizes, int n_in,
                              void* d_out, int out_size, void* d_ws, size_t ws_size,
                              hipStream_t stream)
{
  const float* x     = (const float*)d_in[0];
  const float* w_qkv = (const float*)d_in[1];
  const float* w_out = (const float*)d_in[2];
  const float* b_out = (const float*)d_in[3];

  short* qk_ws   = (short*)d_ws;                         // 4096*2048 = 16 MB
  short* vt_ws   = qk_ws  + (size_t)NTOK * 2048;         // 4096*1024 =  8 MB
  short* x_bf    = vt_ws  + (size_t)NTOK * CDIM;         // 4096*1024 =  8 MB
  short* attn_ws = x_bf;                                 // alias (x_bf dead)
  short* wqkv_bf = x_bf   + (size_t)NTOK * CDIM;         // 3072*1024 =  6 MB
  short* wout_bf = wqkv_bf + (size_t)3 * CDIM * CDIM;    // 1024*1024 =  2 MB

  dim3 blk(256);

  cvt_all<<<dim3(4096), blk, 0, stream>>>(x, w_qkv, w_out, x_bf, wqkv_bf, wout_bf);

  gemm128<0, 128><<<dim3(3 * CDIM / 128, NTOK / 128), blk, 0, stream>>>(
      x_bf, wqkv_bf, nullptr, qk_ws, vt_ws, NTOK, 3 * CDIM, CDIM);

  attn_kernel<<<dim3(BATCH * NH, SEQ / 64), blk, 0, stream>>>(qk_ws, vt_ws, attn_ws);

  gemm128<1, 64><<<dim3(CDIM / 64, NTOK / 128), blk, 0, stream>>>(
      attn_ws, wout_bf, b_out, d_out, nullptr, NTOK, CDIM, CDIM);
}